// Round 1
// baseline (335.584 us; speedup 1.0000x reference)
//
#include <hip/hip_runtime.h>
#include <hip/hip_bf16.h>

#define NN 169
#define NE 5408
#define F 1024
#define NPIX (NN * F)  // 173056

// ---------------------------------------------------------------------------
// 1) segment_sum: h[dst[e]] += input[src[e]]  (block per destination node)
// ---------------------------------------------------------------------------
__global__ __launch_bounds__(256) void segsum_kernel(
    const float* __restrict__ input, const int* __restrict__ src,
    const int* __restrict__ dst, float* __restrict__ hsum) {
  __shared__ int s_list[NE];
  __shared__ int s_count;
  const int node = blockIdx.x;
  const int tid = threadIdx.x;
  if (tid == 0) s_count = 0;
  __syncthreads();
  for (int e = tid; e < NE; e += 256) {
    if (dst[e] == node) {
      int p = atomicAdd(&s_count, 1);
      s_list[p] = src[e];
    }
  }
  __syncthreads();
  const int cnt = s_count;
  float4 acc = make_float4(0.f, 0.f, 0.f, 0.f);
  const float4* in4 = reinterpret_cast<const float4*>(input);
  for (int i = 0; i < cnt; ++i) {
    const int s = s_list[i];
    float4 v = in4[s * 256 + tid];
    acc.x += v.x; acc.y += v.y; acc.z += v.z; acc.w += v.w;
  }
  reinterpret_cast<float4*>(hsum)[node * 256 + tid] = acc;
}

// ---------------------------------------------------------------------------
// 2) hlin = hsum @ W_lin^T + b_lin   (fp32 tiled GEMM, 64x64 tile, 4x4/thread)
//    out[m][n] = sum_k hsum[m][k] * W[n][k] + b[n]
// ---------------------------------------------------------------------------
__global__ __launch_bounds__(256) void gemm_kernel(
    const float* __restrict__ A, const float* __restrict__ W,
    const float* __restrict__ bias, float* __restrict__ C) {
  __shared__ float As[16][65];
  __shared__ float Bs[16][65];
  const int bm = blockIdx.y * 64;
  const int bn = blockIdx.x * 64;
  const int tid = threadIdx.x;
  const int tx = tid & 15;        // 16 col-groups
  const int ty = tid >> 4;        // 16 row-groups
  const int lr = tid >> 2;        // loader row 0..63
  const int lk = (tid & 3) * 4;   // loader k-quad
  float acc[4][4] = {};
  for (int k0 = 0; k0 < 1024; k0 += 16) {
    float4 av = make_float4(0.f, 0.f, 0.f, 0.f);
    const int gm = bm + lr;
    if (gm < NN) av = *reinterpret_cast<const float4*>(&A[gm * 1024 + k0 + lk]);
    As[lk + 0][lr] = av.x; As[lk + 1][lr] = av.y;
    As[lk + 2][lr] = av.z; As[lk + 3][lr] = av.w;
    float4 bv = *reinterpret_cast<const float4*>(&W[(bn + lr) * 1024 + k0 + lk]);
    Bs[lk + 0][lr] = bv.x; Bs[lk + 1][lr] = bv.y;
    Bs[lk + 2][lr] = bv.z; Bs[lk + 3][lr] = bv.w;
    __syncthreads();
#pragma unroll
    for (int k = 0; k < 16; ++k) {
      float a0[4], b0[4];
#pragma unroll
      for (int i = 0; i < 4; ++i) a0[i] = As[k][ty * 4 + i];
#pragma unroll
      for (int j = 0; j < 4; ++j) b0[j] = Bs[k][tx * 4 + j];
#pragma unroll
      for (int i = 0; i < 4; ++i)
#pragma unroll
        for (int j = 0; j < 4; ++j) acc[i][j] += a0[i] * b0[j];
    }
    __syncthreads();
  }
#pragma unroll
  for (int i = 0; i < 4; ++i) {
    const int m = bm + ty * 4 + i;
    if (m < NN) {
#pragma unroll
      for (int j = 0; j < 4; ++j) {
        const int n = bn + tx * 4 + j;
        C[m * 1024 + n] = acc[i][j] + bias[n];
      }
    }
  }
}

// ---------------------------------------------------------------------------
// 3) transpose W2 (32,64,3,3) -> w2t[(ic*9+k)*32 + oc]  (oc contiguous)
// ---------------------------------------------------------------------------
__global__ __launch_bounds__(256) void w2t_kernel(const float* __restrict__ W2,
                                                  float* __restrict__ w2t) {
  const int j = blockIdx.x * 256 + threadIdx.x;
  if (j >= 32 * 64 * 9) return;
  const int oc = j & 31;
  const int t = j >> 5;  // ic*9 + k
  w2t[j] = W2[oc * 576 + t];
}

// ---------------------------------------------------------------------------
// 4) fused conv1(1->64)+relu -> conv2(64->32)+relu.
//    conv1 tile (incl. halo) is computed on the fly into LDS (never hits HBM).
//    Tile: 4 rows x 64 cols, 1 pixel/thread, 32 oc accumulators.
// ---------------------------------------------------------------------------
__global__ __launch_bounds__(256) void conv12_kernel(
    const float* __restrict__ hlin, const float* __restrict__ W1,
    const float* __restrict__ b1, const float* __restrict__ w2t,
    const float* __restrict__ b2, float* __restrict__ h2) {
  __shared__ float s_h[8][68];        // hlin tile rows y0-2..y0+5, cols x0-2..x0+65
  __shared__ float s_w1[576];
  __shared__ float s_in[8][6][66];    // conv1 output chunk (8 ic, halo'd)
  __shared__ float s_w2[8 * 288];     // w2t chunk
  const int x0 = blockIdx.x * 64;
  const int y0 = blockIdx.y * 4;
  const int tid = threadIdx.x;
  const int ty = tid >> 6, tx = tid & 63;
  const int y = y0 + ty, x = x0 + tx;

  for (int idx = tid; idx < 576; idx += 256) s_w1[idx] = W1[idx];
  for (int idx = tid; idx < 8 * 68; idx += 256) {
    const int r = idx / 68, xx = idx - r * 68;
    const int gy = y0 - 2 + r, gx = x0 - 2 + xx;
    s_h[r][xx] = (gy >= 0 && gy < NN && gx >= 0 && gx < 1024)
                     ? hlin[gy * 1024 + gx] : 0.f;
  }

  float acc[32];
#pragma unroll
  for (int oc = 0; oc < 32; ++oc) acc[oc] = b2[oc];

  for (int cb = 0; cb < 64; cb += 8) {
    __syncthreads();  // first iter: covers s_h/s_w1; later: protects s_in/s_w2
    for (int idx = tid; idx < 8 * 288; idx += 256)
      s_w2[idx] = w2t[cb * 288 + idx];
    // compute conv1 chunk (8 input channels of conv2) into s_in
    for (int idx = tid; idx < 8 * 6 * 66; idx += 256) {
      const int c = idx / 396;
      const int rem = idx - c * 396;
      const int r = rem / 66, xx = rem - r * 66;
      const int gy = y0 - 1 + r, gx = x0 - 1 + xx;
      float v = 0.f;
      if (gy >= 0 && gy < NN && gx >= 0 && gx < 1024) {
        const int ic = cb + c;
        float a = b1[ic];
#pragma unroll
        for (int ky = 0; ky < 3; ++ky)
#pragma unroll
          for (int kx = 0; kx < 3; ++kx)
            a += s_h[r + ky][xx + kx] * s_w1[ic * 9 + ky * 3 + kx];
        v = fmaxf(a, 0.f);
      }
      s_in[c][r][xx] = v;
    }
    __syncthreads();
    for (int c = 0; c < 8; ++c) {
#pragma unroll
      for (int k = 0; k < 9; ++k) {
        const int ky = k / 3, kx = k % 3;
        const float iv = s_in[c][ty + ky][tx + kx];
        const float4* w4 = reinterpret_cast<const float4*>(&s_w2[(c * 9 + k) * 32]);
#pragma unroll
        for (int o4 = 0; o4 < 8; ++o4) {
          const float4 wv = w4[o4];
          acc[o4 * 4 + 0] += iv * wv.x;
          acc[o4 * 4 + 1] += iv * wv.y;
          acc[o4 * 4 + 2] += iv * wv.z;
          acc[o4 * 4 + 3] += iv * wv.w;
        }
      }
    }
  }
  if (y < NN) {
#pragma unroll
    for (int oc = 0; oc < 32; ++oc)
      h2[oc * NPIX + y * 1024 + x] = fmaxf(acc[oc], 0.f);
  }
}

// ---------------------------------------------------------------------------
// 5) conv3 (32->1) + relu -> d_out
// ---------------------------------------------------------------------------
__global__ __launch_bounds__(256) void conv3_kernel(
    const float* __restrict__ h2, const float* __restrict__ W3,
    const float* __restrict__ b3, float* __restrict__ out) {
  __shared__ float s_in[32][6][66];  // 50.7 KB
  __shared__ float s_w3[288];
  const int x0 = blockIdx.x * 64;
  const int y0 = blockIdx.y * 4;
  const int tid = threadIdx.x;
  const int ty = tid >> 6, tx = tid & 63;
  for (int idx = tid; idx < 288; idx += 256) s_w3[idx] = W3[idx];
  for (int idx = tid; idx < 32 * 6 * 66; idx += 256) {
    const int c = idx / 396;
    const int rem = idx - c * 396;
    const int r = rem / 66, xx = rem - r * 66;
    const int gy = y0 - 1 + r, gx = x0 - 1 + xx;
    s_in[c][r][xx] = (gy >= 0 && gy < NN && gx >= 0 && gx < 1024)
                         ? h2[c * NPIX + gy * 1024 + gx] : 0.f;
  }
  __syncthreads();
  const int y = y0 + ty, x = x0 + tx;
  float acc = b3[0];
  for (int c = 0; c < 32; ++c) {
#pragma unroll
    for (int k = 0; k < 9; ++k)
      acc += s_in[c][ty + k / 3][tx + k % 3] * s_w3[c * 9 + k];
  }
  if (y < NN) out[y * 1024 + x] = fmaxf(acc, 0.f);
}

// ---------------------------------------------------------------------------
extern "C" void kernel_launch(void* const* d_in, const int* in_sizes, int n_in,
                              void* d_out, int out_size, void* d_ws, size_t ws_size,
                              hipStream_t stream) {
  const float* input = (const float*)d_in[0];
  const int*   src   = (const int*)d_in[1];
  const int*   dst   = (const int*)d_in[2];
  const float* W_lin = (const float*)d_in[3];
  const float* b_lin = (const float*)d_in[4];
  const float* W1    = (const float*)d_in[5];
  const float* b1    = (const float*)d_in[6];
  const float* W2    = (const float*)d_in[7];
  const float* b2    = (const float*)d_in[8];
  const float* W3    = (const float*)d_in[9];
  const float* b3    = (const float*)d_in[10];
  float* out = (float*)d_out;

  // workspace layout (floats): hsum | hlin | w2t | h2  => ~23.6 MB total
  float* hsum = (float*)d_ws;
  float* hlin = hsum + NPIX;
  float* w2t  = hlin + NPIX;
  float* h2   = w2t + 64 * 9 * 32;

  segsum_kernel<<<NN, 256, 0, stream>>>(input, src, dst, hsum);
  gemm_kernel<<<dim3(16, 3), 256, 0, stream>>>(hsum, W_lin, b_lin, hlin);
  w2t_kernel<<<72, 256, 0, stream>>>(W2, w2t);
  conv12_kernel<<<dim3(16, 43), 256, 0, stream>>>(hlin, W1, b1, w2t, b2, h2);
  conv3_kernel<<<dim3(16, 43), 256, 0, stream>>>(h2, W3, b3, out);
}

// Round 2
// 311.498 us; speedup vs baseline: 1.0773x; 1.0773x over previous
//
#include <hip/hip_runtime.h>
#include <hip/hip_bf16.h>

#define NN 169
#define NE 5408
#define F 1024
#define NPIX (NN * F)  // 173056

// ---------------------------------------------------------------------------
// 1) segment_sum: h[dst[e]] += input[src[e]]
//    grid (node, feature-chunk/256): 676 blocks. Each block scans all edges,
//    compacts matches into LDS, then accumulates its 256-feature slice.
// ---------------------------------------------------------------------------
__global__ __launch_bounds__(256) void segsum_kernel(
    const float* __restrict__ input, const int* __restrict__ src,
    const int* __restrict__ dst, float* __restrict__ hsum) {
  __shared__ int s_list[NE];
  __shared__ int s_count;
  const int node = blockIdx.x;
  const int fbase = blockIdx.y * 256;
  const int tid = threadIdx.x;
  if (tid == 0) s_count = 0;
  __syncthreads();
  for (int e = tid; e < NE; e += 256) {
    if (dst[e] == node) {
      int p = atomicAdd(&s_count, 1);
      s_list[p] = src[e];
    }
  }
  __syncthreads();
  const int cnt = s_count;
  const int f = fbase + tid;
  float acc = 0.f;
  for (int i = 0; i < cnt; ++i) acc += input[s_list[i] * F + f];
  hsum[node * F + f] = acc;
}

// ---------------------------------------------------------------------------
// 2) gemm split-K: gpart[kz][m][n] = sum_{k in chunk kz} A[m][k]*W[n][k]
//    BM=32, BN=64, 8 K-chunks of 128. grid (16,6,8)=768 blocks.
// ---------------------------------------------------------------------------
#define KSPLIT 8
#define KCHUNK (1024 / KSPLIT)
__global__ __launch_bounds__(256) void gemm_kernel(
    const float* __restrict__ A, const float* __restrict__ W,
    float* __restrict__ gpart) {
  __shared__ float As[16][33];
  __shared__ float Bs[16][68];
  const int n0 = blockIdx.x * 64;
  const int m0 = blockIdx.y * 32;
  const int kz = blockIdx.z;
  const int tid = threadIdx.x;
  const int tx = tid & 15;   // n-quad
  const int ty = tid >> 4;   // m-pair
  // loaders
  const int ar = tid >> 3, ak = (tid & 7) * 2;   // A: 32 rows x 8 k-pairs
  const int br = tid >> 2, bk = (tid & 3) * 4;   // B: 64 rows x 4 k-quads
  float acc[2][4] = {};
  for (int k0 = kz * KCHUNK; k0 < (kz + 1) * KCHUNK; k0 += 16) {
    float2 av = make_float2(0.f, 0.f);
    if (m0 + ar < NN)
      av = *reinterpret_cast<const float2*>(&A[(m0 + ar) * F + k0 + ak]);
    As[ak][ar] = av.x; As[ak + 1][ar] = av.y;
    float4 bv = *reinterpret_cast<const float4*>(&W[(n0 + br) * F + k0 + bk]);
    Bs[bk][br] = bv.x; Bs[bk + 1][br] = bv.y;
    Bs[bk + 2][br] = bv.z; Bs[bk + 3][br] = bv.w;
    __syncthreads();
#pragma unroll
    for (int k = 0; k < 16; ++k) {
      const float a0 = As[k][ty * 2], a1 = As[k][ty * 2 + 1];
      const float4 b = *reinterpret_cast<const float4*>(&Bs[k][tx * 4]);
      acc[0][0] += a0 * b.x; acc[0][1] += a0 * b.y;
      acc[0][2] += a0 * b.z; acc[0][3] += a0 * b.w;
      acc[1][0] += a1 * b.x; acc[1][1] += a1 * b.y;
      acc[1][2] += a1 * b.z; acc[1][3] += a1 * b.w;
    }
    __syncthreads();
  }
#pragma unroll
  for (int i = 0; i < 2; ++i) {
    const int m = m0 + ty * 2 + i;
    if (m < NN)
      *reinterpret_cast<float4*>(&gpart[kz * NPIX + m * F + n0 + tx * 4]) =
          make_float4(acc[i][0], acc[i][1], acc[i][2], acc[i][3]);
  }
}

// hlin = sum of partials + bias
__global__ __launch_bounds__(256) void reduce_kernel(
    const float* __restrict__ gpart, const float* __restrict__ bias,
    float* __restrict__ hlin) {
  const int i = blockIdx.x * 256 + threadIdx.x;  // grid covers NPIX exactly
  float a = 0.f;
#pragma unroll
  for (int z = 0; z < KSPLIT; ++z) a += gpart[z * NPIX + i];
  hlin[i] = a + bias[i & (F - 1)];
}

// ---------------------------------------------------------------------------
// 3) transpose W2 (32,64,3,3) -> w2t[g][(ic*9+k)*16 + o], g = oc>>4, o = oc&15
// ---------------------------------------------------------------------------
__global__ __launch_bounds__(256) void w2t_kernel(const float* __restrict__ W2,
                                                  float* __restrict__ w2t) {
  const int j = blockIdx.x * 256 + threadIdx.x;
  if (j >= 32 * 64 * 9) return;
  const int g = j / 9216;
  const int rem = j - g * 9216;
  const int t = rem >> 4;   // ic*9+k
  const int o = rem & 15;
  w2t[j] = W2[(g * 16 + o) * 576 + t];
}

// ---------------------------------------------------------------------------
// 4) fused conv1(1->64)+relu -> conv2(64->32)+relu, oc split 2-way.
//    grid (16,43,2) = 1376 blocks. Each block: 4x64 pixel tile, 16 oc.
// ---------------------------------------------------------------------------
__global__ __launch_bounds__(256) void conv12_kernel(
    const float* __restrict__ hlin, const float* __restrict__ W1,
    const float* __restrict__ b1, const float* __restrict__ w2t,
    const float* __restrict__ b2, float* __restrict__ h2) {
  __shared__ float s_h[8][68];      // hlin tile + halo(2)
  __shared__ float s_w1[576];
  __shared__ float s_in[8][6][66];  // conv1 chunk (8 ic, halo 1)
  __shared__ float s_w2[1152];      // 8 ic * 9 k * 16 oc
  const int x0 = blockIdx.x * 64;
  const int y0 = blockIdx.y * 4;
  const int g = blockIdx.z;         // oc group
  const int ocb = g * 16;
  const int tid = threadIdx.x;
  const int ty = tid >> 6, tx = tid & 63;
  const int y = y0 + ty, x = x0 + tx;

  for (int idx = tid; idx < 576; idx += 256) s_w1[idx] = W1[idx];
  for (int idx = tid; idx < 8 * 68; idx += 256) {
    const int r = idx / 68, xx = idx - r * 68;
    const int gy = y0 - 2 + r, gx = x0 - 2 + xx;
    s_h[r][xx] = (gy >= 0 && gy < NN && gx >= 0 && gx < 1024)
                     ? hlin[gy * 1024 + gx] : 0.f;
  }

  float acc[16];
#pragma unroll
  for (int o = 0; o < 16; ++o) acc[o] = b2[ocb + o];

  for (int cb = 0; cb < 64; cb += 8) {
    __syncthreads();  // first iter: covers s_h/s_w1; later: protects s_in/s_w2
    for (int idx = tid; idx < 1152; idx += 256)
      s_w2[idx] = w2t[g * 9216 + cb * 144 + idx];
    for (int idx = tid; idx < 8 * 6 * 66; idx += 256) {
      const int c = idx / 396;
      const int rem = idx - c * 396;
      const int r = rem / 66, xx = rem - r * 66;
      const int gy = y0 - 1 + r, gx = x0 - 1 + xx;
      float v = 0.f;
      if (gy >= 0 && gy < NN && gx >= 0 && gx < 1024) {
        const int ic = cb + c;
        float a = b1[ic];
#pragma unroll
        for (int ky = 0; ky < 3; ++ky)
#pragma unroll
          for (int kx = 0; kx < 3; ++kx)
            a += s_h[r + ky][xx + kx] * s_w1[ic * 9 + ky * 3 + kx];
        v = fmaxf(a, 0.f);
      }
      s_in[c][r][xx] = v;
    }
    __syncthreads();
    for (int c = 0; c < 8; ++c) {
#pragma unroll
      for (int k = 0; k < 9; ++k) {
        const int ky = k / 3, kx = k % 3;
        const float iv = s_in[c][ty + ky][tx + kx];
        const float4* w4 = reinterpret_cast<const float4*>(&s_w2[(c * 9 + k) * 16]);
#pragma unroll
        for (int o4 = 0; o4 < 4; ++o4) {
          const float4 wv = w4[o4];
          acc[o4 * 4 + 0] += iv * wv.x;
          acc[o4 * 4 + 1] += iv * wv.y;
          acc[o4 * 4 + 2] += iv * wv.z;
          acc[o4 * 4 + 3] += iv * wv.w;
        }
      }
    }
  }
  if (y < NN) {
#pragma unroll
    for (int o = 0; o < 16; ++o)
      h2[(ocb + o) * NPIX + y * 1024 + x] = fmaxf(acc[o], 0.f);
  }
}

// ---------------------------------------------------------------------------
// 5) conv3 (32->1) + relu -> d_out
// ---------------------------------------------------------------------------
__global__ __launch_bounds__(256) void conv3_kernel(
    const float* __restrict__ h2, const float* __restrict__ W3,
    const float* __restrict__ b3, float* __restrict__ out) {
  __shared__ float s_in[32][6][66];
  __shared__ float s_w3[288];
  const int x0 = blockIdx.x * 64;
  const int y0 = blockIdx.y * 4;
  const int tid = threadIdx.x;
  const int ty = tid >> 6, tx = tid & 63;
  for (int idx = tid; idx < 288; idx += 256) s_w3[idx] = W3[idx];
  for (int idx = tid; idx < 32 * 6 * 66; idx += 256) {
    const int c = idx / 396;
    const int rem = idx - c * 396;
    const int r = rem / 66, xx = rem - r * 66;
    const int gy = y0 - 1 + r, gx = x0 - 1 + xx;
    s_in[c][r][xx] = (gy >= 0 && gy < NN && gx >= 0 && gx < 1024)
                         ? h2[c * NPIX + gy * 1024 + gx] : 0.f;
  }
  __syncthreads();
  const int y = y0 + ty, x = x0 + tx;
  float acc = b3[0];
  for (int c = 0; c < 32; ++c) {
#pragma unroll
    for (int k = 0; k < 9; ++k)
      acc += s_in[c][ty + k / 3][tx + k % 3] * s_w3[c * 9 + k];
  }
  if (y < NN) out[y * 1024 + x] = fmaxf(acc, 0.f);
}

// ---------------------------------------------------------------------------
extern "C" void kernel_launch(void* const* d_in, const int* in_sizes, int n_in,
                              void* d_out, int out_size, void* d_ws, size_t ws_size,
                              hipStream_t stream) {
  const float* input = (const float*)d_in[0];
  const int*   src   = (const int*)d_in[1];
  const int*   dst   = (const int*)d_in[2];
  const float* W_lin = (const float*)d_in[3];
  const float* b_lin = (const float*)d_in[4];
  const float* W1    = (const float*)d_in[5];
  const float* b1    = (const float*)d_in[6];
  const float* W2    = (const float*)d_in[7];
  const float* b2    = (const float*)d_in[8];
  const float* W3    = (const float*)d_in[9];
  const float* b3    = (const float*)d_in[10];
  float* out = (float*)d_out;

  // ws layout (floats): hsum | hlin | w2t | h2(32*NPIX)  ~= 23.6 MB
  // gemm partials (8*NPIX = 5.5 MB) alias the h2 region (h2 written later).
  float* hsum = (float*)d_ws;
  float* hlin = hsum + NPIX;
  float* w2t  = hlin + NPIX;
  float* h2   = w2t + 64 * 9 * 32;
  float* gpart = h2;

  segsum_kernel<<<dim3(NN, 4), 256, 0, stream>>>(input, src, dst, hsum);
  gemm_kernel<<<dim3(16, 6, KSPLIT), 256, 0, stream>>>(hsum, W_lin, gpart);
  w2t_kernel<<<72, 256, 0, stream>>>(W2, w2t);
  reduce_kernel<<<NPIX / 256, 256, 0, stream>>>(gpart, b_lin, hlin);
  conv12_kernel<<<dim3(16, 43, 2), 256, 0, stream>>>(hlin, W1, b1, w2t, b2, h2);
  conv3_kernel<<<dim3(16, 43), 256, 0, stream>>>(h2, W3, b3, out);
}